// Round 1
// baseline (2269.729 us; speedup 1.0000x reference)
//
#include <hip/hip_runtime.h>
#include <math.h>

#define NHID 8
#define NHEADS 8
#define EMB 64
#define NPROT 2048
#define NDRUG 1500
#define NPAIR 16384

// ---------------- GAT: Wh[h][n][o] = sum_f h[n,f] * W[h,f,o] ----------------
__global__ void k_gat_wh(const float* __restrict__ h, const float* __restrict__ W,
                         float* __restrict__ Wh, int N, int F) {
    int idx = blockIdx.x * 256 + threadIdx.x;       // flat (hh, n, o)
    int total = NHEADS * N * NHID;
    if (idx >= total) return;
    int o  = idx & 7;
    int n  = (idx >> 3) % N;
    int hh = idx / (N * 8);
    const float* hp = h + (size_t)n * F;
    const float* wp = W + (size_t)hh * F * 8 + o;
    float acc = 0.f;
    for (int f = 0; f < F; ++f) acc += hp[f] * wp[(size_t)f * 8];
    Wh[idx] = acc;
}

// s1[h][n] = Wh[h][n][:] . a[h][:8];  s2 uses a[h][8:16]
__global__ void k_gat_s(const float* __restrict__ Wh, const float* __restrict__ a,
                        float* __restrict__ s1, float* __restrict__ s2, int N) {
    int idx = blockIdx.x * 256 + threadIdx.x;       // h*N + n
    if (idx >= NHEADS * N) return;
    int hh = idx / N;
    const float* wp = Wh + (size_t)idx * 8;
    const float* ap = a + hh * 16;
    float x1 = 0.f, x2 = 0.f;
    for (int o = 0; o < 8; ++o) { x1 += wp[o] * ap[o]; x2 += wp[o] * ap[8 + o]; }
    s1[idx] = x1; s2[idx] = x2;
}

// One block per row i: build neighbor list, then per head: masked softmax + PV
__global__ void k_gat_attn(const float* __restrict__ adj, const float* __restrict__ s1,
                           const float* __restrict__ s2, const float* __restrict__ Wh,
                           float* __restrict__ out, int N) {
    __shared__ int   nbr[2048];
    __shared__ int   s_cnt;
    __shared__ float wmax[4];
    __shared__ float s_max;
    __shared__ float red[4 * 9];
    int i = blockIdx.x;
    int tid = threadIdx.x;
    if (tid == 0) s_cnt = 0;
    __syncthreads();
    const float* arow = adj + (size_t)i * N;
    for (int j = tid; j < N; j += 256)
        if (arow[j] > 0.f) { int p = atomicAdd(&s_cnt, 1); nbr[p] = j; }
    __syncthreads();
    int cnt = s_cnt;
    int wv = tid >> 6, ln = tid & 63;
    for (int hh = 0; hh < NHEADS; ++hh) {
        float si = s1[hh * N + i];
        const float* s2h = s2 + hh * N;
        // pass 1: row max of leakyrelu(si + s2[j])
        float mx = -1e30f;
        for (int t = tid; t < cnt; t += 256) {
            float e = si + s2h[nbr[t]];
            e = e > 0.f ? e : 0.2f * e;
            mx = fmaxf(mx, e);
        }
        for (int off = 32; off; off >>= 1) mx = fmaxf(mx, __shfl_down(mx, off, 64));
        if (ln == 0) wmax[wv] = mx;
        __syncthreads();
        if (tid == 0) s_max = fmaxf(fmaxf(wmax[0], wmax[1]), fmaxf(wmax[2], wmax[3]));
        __syncthreads();
        float m = s_max;
        // pass 2: exp-sum and weighted accumulation of Wh rows
        float acc[8] = {0, 0, 0, 0, 0, 0, 0, 0};
        float lsum = 0.f;
        for (int t = tid; t < cnt; t += 256) {
            int j = nbr[t];
            float e = si + s2h[j];
            e = e > 0.f ? e : 0.2f * e;
            float p = __expf(e - m);
            lsum += p;
            const float* wp = Wh + ((size_t)hh * N + j) * 8;
            for (int o = 0; o < 8; ++o) acc[o] += p * wp[o];
        }
        for (int off = 32; off; off >>= 1) {
            lsum += __shfl_down(lsum, off, 64);
            for (int o = 0; o < 8; ++o) acc[o] += __shfl_down(acc[o], off, 64);
        }
        if (ln == 0) {
            red[wv * 9 + 8] = lsum;
            for (int o = 0; o < 8; ++o) red[wv * 9 + o] = acc[o];
        }
        __syncthreads();
        if (tid < 8) {
            float s = red[8] + red[9 + 8] + red[18 + 8] + red[27 + 8];
            float a0 = red[tid] + red[9 + tid] + red[18 + tid] + red[27 + tid];
            float r = a0 / s;
            out[(size_t)i * 64 + hh * 8 + tid] = r > 0.f ? r : 0.f;   // relu
        }
        __syncthreads();
    }
}

// out[n][o] = sum_d in[n][d] * W[o][d]   (x @ W.T, no bias)
__global__ void k_proj(const float* __restrict__ in, const float* __restrict__ W,
                       float* __restrict__ out, int N) {
    int idx = blockIdx.x * 256 + threadIdx.x;
    if (idx >= N * 64) return;
    int o = idx & 63, n = idx >> 6;
    const float* ip = in + (size_t)n * 64;
    const float* wp = W + (size_t)o * 64;
    float acc = 0.f;
    for (int d = 0; d < 64; ++d) acc += ip[d] * wp[d];
    out[idx] = acc;
}

// qkv[sm][n][o] = b[sm][o] + sum_d x[n][d] * W[sm][o][d],  sm in [0,24)
__global__ void k_qkv(const float* __restrict__ x, const float* __restrict__ W,
                      const float* __restrict__ b, float* __restrict__ qkv, int N) {
    int idx = blockIdx.x * 256 + threadIdx.x;
    int total = 24 * N * 64;
    if (idx >= total) return;
    int o = idx & 63;
    int n = (idx >> 6) % N;
    int sm = idx / (N * 64);
    const float* xp = x + (size_t)n * 64;
    const float* wp = W + ((size_t)sm * 64 + o) * 64;
    float acc = b[sm * 64 + o];
    for (int d = 0; d < 64; ++d) acc += xp[d] * wp[d];
    qkv[idx] = acc;
}

// Flash attention per (module m, head h), hd=8. atomicAdd the module-sum.
__global__ void k_attn(const float* __restrict__ qkv, float* __restrict__ accum, int N) {
    __shared__ float kt[256][8];
    __shared__ float vt[256][8];
    int m = blockIdx.x >> 3, hh = blockIdx.x & 7;
    int r = blockIdx.y * 256 + threadIdx.x;
    const float* qbase = qkv + (size_t)m * N * 64;
    const float* kbase = qkv + (size_t)(8 + m) * N * 64;
    const float* vbase = qkv + (size_t)(16 + m) * N * 64;
    float q[8];
    if (r < N)
        for (int d = 0; d < 8; ++d) q[d] = qbase[(size_t)r * 64 + hh * 8 + d];
    float mx = -1e30f, l = 0.f, acc[8] = {0, 0, 0, 0, 0, 0, 0, 0};
    const float scale = 0.35355339059327373f;   // 1/sqrt(8)
    for (int tile = 0; tile < N; tile += 256) {
        int j = tile + threadIdx.x;
        if (j < N) {
            const float* kp = kbase + (size_t)j * 64 + hh * 8;
            const float* vp = vbase + (size_t)j * 64 + hh * 8;
            for (int d = 0; d < 8; ++d) { kt[threadIdx.x][d] = kp[d]; vt[threadIdx.x][d] = vp[d]; }
        }
        __syncthreads();
        int lim = min(256, N - tile);
        if (r < N) {
            for (int jj = 0; jj < lim; ++jj) {
                float s = 0.f;
                for (int d = 0; d < 8; ++d) s += q[d] * kt[jj][d];
                s *= scale;
                if (s > mx) {
                    float corr = __expf(mx - s);
                    l = l * corr + 1.f;
                    for (int d = 0; d < 8; ++d) acc[d] = acc[d] * corr + vt[jj][d];
                    mx = s;
                } else {
                    float p = __expf(s - mx);
                    l += p;
                    for (int d = 0; d < 8; ++d) acc[d] += p * vt[jj][d];
                }
            }
        }
        __syncthreads();
    }
    if (r < N) {
        float inv = 1.f / l;
        for (int d = 0; d < 8; ++d)
            atomicAdd(&accum[(size_t)r * 64 + hh * 8 + d], acc[d] * inv);
    }
}

// out = LN(acc + resid) * g + b ; one wave (64 lanes) per row
__global__ void k_ln(const float* __restrict__ acc, const float* __restrict__ resid,
                     const float* __restrict__ g, const float* __restrict__ b,
                     float* __restrict__ out, int N) {
    int r = blockIdx.x * 4 + (threadIdx.x >> 6);
    int d = threadIdx.x & 63;
    if (r >= N) return;
    float v = acc[(size_t)r * 64 + d] + resid[(size_t)r * 64 + d];
    float s = v;
    for (int off = 32; off; off >>= 1) s += __shfl_xor(s, off, 64);
    float mean = s * (1.f / 64.f);
    float c = v - mean;
    float vv = c * c;
    for (int off = 32; off; off >>= 1) vv += __shfl_xor(vv, off, 64);
    float var = vv * (1.f / 64.f);
    out[(size_t)r * 64 + d] = c * rsqrtf(var + 1e-5f) * g[d] + b[d];
}

// Final MLP: gather concat -> fc1 relu -> fc2 relu -> fc3. One block per pair.
__global__ void k_mlp(const float* __restrict__ px, const float* __restrict__ dx,
                      const int* __restrict__ pairs,
                      const float* __restrict__ W1, const float* __restrict__ b1,
                      const float* __restrict__ W2, const float* __restrict__ b2,
                      const float* __restrict__ W3, const float* __restrict__ b3,
                      float* __restrict__ out) {
    __shared__ float xin[128], h1[128], h2[128];
    __shared__ float wred[2];
    int bId = blockIdx.x;
    int t = threadIdx.x;
    int ip = pairs[bId * 2], id = pairs[bId * 2 + 1];
    xin[t] = (t < 64) ? px[(size_t)ip * 64 + t] : dx[(size_t)id * 64 + (t - 64)];
    __syncthreads();
    float a = b1[t];
    {
        const float* w = W1 + (size_t)t * 128;
        for (int d = 0; d < 128; ++d) a += xin[d] * w[d];
    }
    h1[t] = a > 0.f ? a : 0.f;
    __syncthreads();
    a = b2[t];
    {
        const float* w = W2 + (size_t)t * 128;
        for (int d = 0; d < 128; ++d) a += h1[d] * w[d];
    }
    h2[t] = a > 0.f ? a : 0.f;
    __syncthreads();
    float p = h2[t] * W3[t];
    for (int off = 32; off; off >>= 1) p += __shfl_down(p, off, 64);
    if ((t & 63) == 0) wred[t >> 6] = p;
    __syncthreads();
    if (t == 0) out[bId] = wred[0] + wred[1] + b3[0];
}

extern "C" void kernel_launch(void* const* d_in, const int* in_sizes, int n_in,
                              void* d_out, int out_size, void* d_ws, size_t ws_size,
                              hipStream_t stream) {
    const float* pfeat = (const float*)d_in[0];
    const float* padj  = (const float*)d_in[1];
    const float* dfeat = (const float*)d_in[2];
    const float* dadj  = (const float*)d_in[3];
    const int*   pairs = (const int*)d_in[4];
    const float* fc1W = (const float*)d_in[33];
    const float* fc1b = (const float*)d_in[34];
    const float* fc2W = (const float*)d_in[35];
    const float* fc2b = (const float*)d_in[36];
    const float* fc3W = (const float*)d_in[37];
    const float* fc3b = (const float*)d_in[38];

    float* ws = (float*)d_ws;
    float* buf_Wh   = ws;                              // 8*2048*8   = 131072
    float* buf_s1   = buf_Wh   + 8 * 2048 * 8;         // 16384
    float* buf_s2   = buf_s1   + 8 * 2048;             // 16384
    float* buf_gat  = buf_s2   + 8 * 2048;             // 131072
    float* buf_proj = buf_gat  + 2048 * 64;            // 131072
    float* buf_qkv  = buf_proj + 2048 * 64;            // 3145728
    float* buf_acc  = buf_qkv  + 24 * 2048 * 64;       // 131072
    float* buf_x    = buf_acc  + 2048 * 64;            // 131072
    float* buf_px   = buf_x    + 2048 * 64;            // 131072
    float* buf_dx   = buf_px   + 2048 * 64;            // 96000

    auto run_branch = [&](const float* feat, const float* adj, int N, int F,
                          void* const* w, float* xout) {
        const float* g1W = (const float*)w[0];
        const float* g1a = (const float*)w[1];
        const float* p1W = (const float*)w[2];
        const float* s1W = (const float*)w[3];
        const float* s1b = (const float*)w[4];
        const float* l1g = (const float*)w[5];
        const float* l1b = (const float*)w[6];
        const float* g2W = (const float*)w[7];
        const float* g2a = (const float*)w[8];
        const float* p2W = (const float*)w[9];
        const float* s2W = (const float*)w[10];
        const float* s2b = (const float*)w[11];
        const float* l2g = (const float*)w[12];
        const float* l2b = (const float*)w[13];

        // ---- layer 1 ----
        k_gat_wh<<<(64 * N + 255) / 256, 256, 0, stream>>>(feat, g1W, buf_Wh, N, F);
        k_gat_s<<<(8 * N + 255) / 256, 256, 0, stream>>>(buf_Wh, g1a, buf_s1, buf_s2, N);
        k_gat_attn<<<N, 256, 0, stream>>>(adj, buf_s1, buf_s2, buf_Wh, buf_gat, N);
        k_proj<<<(64 * N + 255) / 256, 256, 0, stream>>>(buf_gat, p1W, buf_proj, N);
        k_qkv<<<(1536 * N + 255) / 256, 256, 0, stream>>>(buf_proj, s1W, s1b, buf_qkv, N);
        hipMemsetAsync(buf_acc, 0, (size_t)N * 64 * sizeof(float), stream);
        k_attn<<<dim3(64, (N + 255) / 256), 256, 0, stream>>>(buf_qkv, buf_acc, N);
        k_ln<<<(N + 3) / 4, 256, 0, stream>>>(buf_acc, buf_proj, l1g, l1b, buf_x, N);
        // ---- layer 2 ----
        k_gat_wh<<<(64 * N + 255) / 256, 256, 0, stream>>>(buf_x, g2W, buf_Wh, N, EMB);
        k_gat_s<<<(8 * N + 255) / 256, 256, 0, stream>>>(buf_Wh, g2a, buf_s1, buf_s2, N);
        k_gat_attn<<<N, 256, 0, stream>>>(adj, buf_s1, buf_s2, buf_Wh, buf_gat, N);
        k_proj<<<(64 * N + 255) / 256, 256, 0, stream>>>(buf_gat, p2W, buf_proj, N);
        k_qkv<<<(1536 * N + 255) / 256, 256, 0, stream>>>(buf_proj, s2W, s2b, buf_qkv, N);
        hipMemsetAsync(buf_acc, 0, (size_t)N * 64 * sizeof(float), stream);
        k_attn<<<dim3(64, (N + 255) / 256), 256, 0, stream>>>(buf_qkv, buf_acc, N);
        k_ln<<<(N + 3) / 4, 256, 0, stream>>>(buf_acc, buf_proj, l2g, l2b, xout, N);
    };

    run_branch(pfeat, padj, NPROT, 512, d_in + 5, buf_px);
    run_branch(dfeat, dadj, NDRUG, 256, d_in + 19, buf_dx);

    k_mlp<<<NPAIR, 128, 0, stream>>>(buf_px, buf_dx, pairs,
                                     fc1W, fc1b, fc2W, fc2b, fc3W, fc3b,
                                     (float*)d_out);
}

// Round 3
// 1848.655 us; speedup vs baseline: 1.2278x; 1.2278x over previous
//
#include <hip/hip_runtime.h>
#include <math.h>

#define NHID 8
#define NHEADS 8
#define EMB 64
#define NPROT 2048
#define NDRUG 1500
#define NPAIR 16384

// ---------------- GAT: Wh[h][n][o] = sum_f h[n,f] * W[h,f,o] ----------------
__global__ void k_gat_wh(const float* __restrict__ h, const float* __restrict__ W,
                         float* __restrict__ Wh, int N, int F) {
    int idx = blockIdx.x * 256 + threadIdx.x;       // flat (hh, n, o)
    int total = NHEADS * N * NHID;
    if (idx >= total) return;
    int o  = idx & 7;
    int n  = (idx >> 3) % N;
    int hh = idx / (N * 8);
    const float* hp = h + (size_t)n * F;
    const float* wp = W + (size_t)hh * F * 8 + o;
    float acc = 0.f;
    for (int f = 0; f < F; ++f) acc += hp[f] * wp[(size_t)f * 8];
    Wh[idx] = acc;
}

// s1[h][n] = Wh[h][n][:] . a[h][:8];  s2 uses a[h][8:16]
__global__ void k_gat_s(const float* __restrict__ Wh, const float* __restrict__ a,
                        float* __restrict__ s1, float* __restrict__ s2, int N) {
    int idx = blockIdx.x * 256 + threadIdx.x;       // h*N + n
    if (idx >= NHEADS * N) return;
    int hh = idx / N;
    const float* wp = Wh + (size_t)idx * 8;
    const float* ap = a + hh * 16;
    float x1 = 0.f, x2 = 0.f;
    for (int o = 0; o < 8; ++o) { x1 += wp[o] * ap[o]; x2 += wp[o] * ap[8 + o]; }
    s1[idx] = x1; s2[idx] = x2;
}

// One block per row i. 8 concurrent head-groups of 32 lanes each.
__global__ void k_gat_attn(const float* __restrict__ adj, const float* __restrict__ s1,
                           const float* __restrict__ s2, const float* __restrict__ Wh,
                           float* __restrict__ out, int N) {
    __shared__ int nbr[2048];
    __shared__ int s_cnt;
    int i = blockIdx.x;
    int tid = threadIdx.x;
    if (tid == 0) s_cnt = 0;
    __syncthreads();
    const float* arow = adj + (size_t)i * N;
    for (int j = tid; j < N; j += 256)
        if (arow[j] > 0.f) { int p = atomicAdd(&s_cnt, 1); nbr[p] = j; }
    __syncthreads();
    int cnt = s_cnt;
    int g  = tid >> 5;          // head index 0..7
    int ln = tid & 31;          // lane within head-group
    float si = s1[g * N + i];
    const float* s2h = s2 + g * N;
    // pass 1: group max of leakyrelu(si + s2[j])
    float mx = -1e30f;
    for (int t = ln; t < cnt; t += 32) {
        float e = si + s2h[nbr[t]];
        e = e > 0.f ? e : 0.2f * e;
        mx = fmaxf(mx, e);
    }
    #pragma unroll
    for (int off = 16; off; off >>= 1) mx = fmaxf(mx, __shfl_xor(mx, off, 32));
    // pass 2: exp-sum + weighted accumulation of Wh rows
    float acc[8] = {0, 0, 0, 0, 0, 0, 0, 0};
    float lsum = 0.f;
    for (int t = ln; t < cnt; t += 32) {
        int j = nbr[t];
        float e = si + s2h[j];
        e = e > 0.f ? e : 0.2f * e;
        float p = __expf(e - mx);
        lsum += p;
        const float4* wp = (const float4*)(Wh + ((size_t)g * N + j) * 8);
        float4 w0 = wp[0], w1 = wp[1];
        acc[0] += p * w0.x; acc[1] += p * w0.y; acc[2] += p * w0.z; acc[3] += p * w0.w;
        acc[4] += p * w1.x; acc[5] += p * w1.y; acc[6] += p * w1.z; acc[7] += p * w1.w;
    }
    #pragma unroll
    for (int off = 16; off; off >>= 1) {
        lsum += __shfl_xor(lsum, off, 32);
        #pragma unroll
        for (int d = 0; d < 8; ++d) acc[d] += __shfl_xor(acc[d], off, 32);
    }
    if (ln == 0) {
        float inv = 1.f / lsum;
        #pragma unroll
        for (int d = 0; d < 8; ++d) {
            float r = acc[d] * inv;
            out[(size_t)i * 64 + g * 8 + d] = r > 0.f ? r : 0.f;   // relu
        }
    }
}

// out[n][o] = sum_d in[n][d] * W[o][d]   (x @ W.T, no bias)
__global__ void k_proj(const float* __restrict__ in, const float* __restrict__ W,
                       float* __restrict__ out, int N) {
    int idx = blockIdx.x * 256 + threadIdx.x;
    if (idx >= N * 64) return;
    int o = idx & 63, n = idx >> 6;
    const float* ip = in + (size_t)n * 64;
    const float* wp = W + (size_t)o * 64;
    float acc = 0.f;
    for (int d = 0; d < 64; ++d) acc += ip[d] * wp[d];
    out[idx] = acc;
}

// qkv[sm][n][o] = b[sm][o] + sum_d x[n][d] * W[sm][o][d],  sm in [0,24)
__global__ void k_qkv(const float* __restrict__ x, const float* __restrict__ W,
                      const float* __restrict__ b, float* __restrict__ qkv, int N) {
    int idx = blockIdx.x * 256 + threadIdx.x;
    int total = 24 * N * 64;
    if (idx >= total) return;
    int o = idx & 63;
    int n = (idx >> 6) % N;
    int sm = idx / (N * 64);
    const float* xp = x + (size_t)n * 64;
    const float* wp = W + ((size_t)sm * 64 + o) * 64;
    float acc = b[sm * 64 + o];
    for (int d = 0; d < 64; ++d) acc += xp[d] * wp[d];
    qkv[idx] = acc;
}

// Flash attention per (module m, head h), hd=8. Chunk-of-8 online softmax:
// exact (chunk-granular max updates), branch once per 8 elements, full ILP.
__global__ void k_attn(const float* __restrict__ qkv, float* __restrict__ accum, int N) {
    __shared__ float4 kt4[256][2];
    __shared__ float4 vt4[256][2];
    int m = blockIdx.x >> 3, hh = blockIdx.x & 7;
    int r = blockIdx.y * 256 + threadIdx.x;
    const float* qbase = qkv + (size_t)m * N * 64;
    const float* kbase = qkv + (size_t)(8 + m) * N * 64;
    const float* vbase = qkv + (size_t)(16 + m) * N * 64;
    float q[8];
    if (r < N) {
        const float4* qp = (const float4*)(qbase + (size_t)r * 64 + hh * 8);
        float4 q0 = qp[0], q1 = qp[1];
        q[0] = q0.x; q[1] = q0.y; q[2] = q0.z; q[3] = q0.w;
        q[4] = q1.x; q[5] = q1.y; q[6] = q1.z; q[7] = q1.w;
    }
    float mx = -1e30f, l = 0.f;
    float acc[8] = {0, 0, 0, 0, 0, 0, 0, 0};
    const float scale = 0.35355339059327373f;   // 1/sqrt(8)
    for (int tile = 0; tile < N; tile += 256) {
        int j = tile + threadIdx.x;
        if (j < N) {
            const float4* kp = (const float4*)(kbase + (size_t)j * 64 + hh * 8);
            const float4* vp = (const float4*)(vbase + (size_t)j * 64 + hh * 8);
            kt4[threadIdx.x][0] = kp[0]; kt4[threadIdx.x][1] = kp[1];
            vt4[threadIdx.x][0] = vp[0]; vt4[threadIdx.x][1] = vp[1];
        }
        __syncthreads();
        int lim = min(256, N - tile);
        if (r < N) {
            int j0 = 0;
            for (; j0 + 8 <= lim; j0 += 8) {
                float s[8];
                #pragma unroll
                for (int u = 0; u < 8; ++u) {
                    float4 k0 = kt4[j0 + u][0], k1 = kt4[j0 + u][1];
                    s[u] = (q[0] * k0.x + q[1] * k0.y + q[2] * k0.z + q[3] * k0.w
                          + q[4] * k1.x + q[5] * k1.y + q[6] * k1.z + q[7] * k1.w) * scale;
                }
                float cmax = fmaxf(fmaxf(fmaxf(s[0], s[1]), fmaxf(s[2], s[3])),
                                   fmaxf(fmaxf(s[4], s[5]), fmaxf(s[6], s[7])));
                if (cmax > mx) {                       // rare after warm-up
                    float corr = __expf(mx - cmax);
                    l *= corr;
                    #pragma unroll
                    for (int d = 0; d < 8; ++d) acc[d] *= corr;
                    mx = cmax;
                }
                #pragma unroll
                for (int u = 0; u < 8; ++u) {
                    float p = __expf(s[u] - mx);
                    l += p;
                    float4 v0 = vt4[j0 + u][0], v1 = vt4[j0 + u][1];
                    acc[0] += p * v0.x; acc[1] += p * v0.y; acc[2] += p * v0.z; acc[3] += p * v0.w;
                    acc[4] += p * v1.x; acc[5] += p * v1.y; acc[6] += p * v1.z; acc[7] += p * v1.w;
                }
            }
            for (; j0 < lim; ++j0) {                   // tail (N=1500 case)
                float4 k0 = kt4[j0][0], k1 = kt4[j0][1];
                float s = (q[0] * k0.x + q[1] * k0.y + q[2] * k0.z + q[3] * k0.w
                         + q[4] * k1.x + q[5] * k1.y + q[6] * k1.z + q[7] * k1.w) * scale;
                float4 v0 = vt4[j0][0], v1 = vt4[j0][1];
                if (s > mx) {
                    float corr = __expf(mx - s);
                    l = l * corr + 1.f;
                    acc[0] = acc[0] * corr + v0.x; acc[1] = acc[1] * corr + v0.y;
                    acc[2] = acc[2] * corr + v0.z; acc[3] = acc[3] * corr + v0.w;
                    acc[4] = acc[4] * corr + v1.x; acc[5] = acc[5] * corr + v1.y;
                    acc[6] = acc[6] * corr + v1.z; acc[7] = acc[7] * corr + v1.w;
                    mx = s;
                } else {
                    float p = __expf(s - mx);
                    l += p;
                    acc[0] += p * v0.x; acc[1] += p * v0.y; acc[2] += p * v0.z; acc[3] += p * v0.w;
                    acc[4] += p * v1.x; acc[5] += p * v1.y; acc[6] += p * v1.z; acc[7] += p * v1.w;
                }
            }
        }
        __syncthreads();
    }
    if (r < N) {
        float inv = 1.f / l;
        #pragma unroll
        for (int d = 0; d < 8; ++d)
            atomicAdd(&accum[(size_t)r * 64 + hh * 8 + d], acc[d] * inv);
    }
}

// out = LN(acc + resid) * g + b ; one wave (64 lanes) per row
__global__ void k_ln(const float* __restrict__ acc, const float* __restrict__ resid,
                     const float* __restrict__ g, const float* __restrict__ b,
                     float* __restrict__ out, int N) {
    int r = blockIdx.x * 4 + (threadIdx.x >> 6);
    int d = threadIdx.x & 63;
    if (r >= N) return;
    float v = acc[(size_t)r * 64 + d] + resid[(size_t)r * 64 + d];
    float s = v;
    for (int off = 32; off; off >>= 1) s += __shfl_xor(s, off, 64);
    float mean = s * (1.f / 64.f);
    float c = v - mean;
    float vv = c * c;
    for (int off = 32; off; off >>= 1) vv += __shfl_xor(vv, off, 64);
    float var = vv * (1.f / 64.f);
    out[(size_t)r * 64 + d] = c * rsqrtf(var + 1e-5f) * g[d] + b[d];
}

// Final MLP: gather concat -> fc1 relu -> fc2 relu -> fc3. One block per pair.
__global__ void k_mlp(const float* __restrict__ px, const float* __restrict__ dx,
                      const int* __restrict__ pairs,
                      const float* __restrict__ W1, const float* __restrict__ b1,
                      const float* __restrict__ W2, const float* __restrict__ b2,
                      const float* __restrict__ W3, const float* __restrict__ b3,
                      float* __restrict__ out) {
    __shared__ float xin[128], h1[128], h2[128];
    __shared__ float wred[2];
    int bId = blockIdx.x;
    int t = threadIdx.x;
    int ip = pairs[bId * 2], id = pairs[bId * 2 + 1];
    xin[t] = (t < 64) ? px[(size_t)ip * 64 + t] : dx[(size_t)id * 64 + (t - 64)];
    __syncthreads();
    float a = b1[t];
    {
        const float* w = W1 + (size_t)t * 128;
        for (int d = 0; d < 128; ++d) a += xin[d] * w[d];
    }
    h1[t] = a > 0.f ? a : 0.f;
    __syncthreads();
    a = b2[t];
    {
        const float* w = W2 + (size_t)t * 128;
        for (int d = 0; d < 128; ++d) a += h1[d] * w[d];
    }
    h2[t] = a > 0.f ? a : 0.f;
    __syncthreads();
    float p = h2[t] * W3[t];
    for (int off = 32; off; off >>= 1) p += __shfl_down(p, off, 64);
    if ((t & 63) == 0) wred[t >> 6] = p;
    __syncthreads();
    if (t == 0) out[bId] = wred[0] + wred[1] + b3[0];
}

extern "C" void kernel_launch(void* const* d_in, const int* in_sizes, int n_in,
                              void* d_out, int out_size, void* d_ws, size_t ws_size,
                              hipStream_t stream) {
    const float* pfeat = (const float*)d_in[0];
    const float* padj  = (const float*)d_in[1];
    const float* dfeat = (const float*)d_in[2];
    const float* dadj  = (const float*)d_in[3];
    const int*   pairs = (const int*)d_in[4];
    const float* fc1W = (const float*)d_in[33];
    const float* fc1b = (const float*)d_in[34];
    const float* fc2W = (const float*)d_in[35];
    const float* fc2b = (const float*)d_in[36];
    const float* fc3W = (const float*)d_in[37];
    const float* fc3b = (const float*)d_in[38];

    float* ws = (float*)d_ws;
    float* buf_Wh   = ws;                              // 8*2048*8   = 131072
    float* buf_s1   = buf_Wh   + 8 * 2048 * 8;         // 16384
    float* buf_s2   = buf_s1   + 8 * 2048;             // 16384
    float* buf_gat  = buf_s2   + 8 * 2048;             // 131072
    float* buf_proj = buf_gat  + 2048 * 64;            // 131072
    float* buf_qkv  = buf_proj + 2048 * 64;            // 3145728
    float* buf_acc  = buf_qkv  + 24 * 2048 * 64;       // 131072
    float* buf_x    = buf_acc  + 2048 * 64;            // 131072
    float* buf_px   = buf_x    + 2048 * 64;            // 131072
    float* buf_dx   = buf_px   + 2048 * 64;            // 96000

    auto run_branch = [&](const float* feat, const float* adj, int N, int F,
                          void* const* w, float* xout) {
        const float* g1W = (const float*)w[0];
        const float* g1a = (const float*)w[1];
        const float* p1W = (const float*)w[2];
        const float* s1W = (const float*)w[3];
        const float* s1b = (const float*)w[4];
        const float* l1g = (const float*)w[5];
        const float* l1b = (const float*)w[6];
        const float* g2W = (const float*)w[7];
        const float* g2a = (const float*)w[8];
        const float* p2W = (const float*)w[9];
        const float* s2W = (const float*)w[10];
        const float* s2b = (const float*)w[11];
        const float* l2g = (const float*)w[12];
        const float* l2b = (const float*)w[13];

        // ---- layer 1 ----
        k_gat_wh<<<(64 * N + 255) / 256, 256, 0, stream>>>(feat, g1W, buf_Wh, N, F);
        k_gat_s<<<(8 * N + 255) / 256, 256, 0, stream>>>(buf_Wh, g1a, buf_s1, buf_s2, N);
        k_gat_attn<<<N, 256, 0, stream>>>(adj, buf_s1, buf_s2, buf_Wh, buf_gat, N);
        k_proj<<<(64 * N + 255) / 256, 256, 0, stream>>>(buf_gat, p1W, buf_proj, N);
        k_qkv<<<(1536 * N + 255) / 256, 256, 0, stream>>>(buf_proj, s1W, s1b, buf_qkv, N);
        hipMemsetAsync(buf_acc, 0, (size_t)N * 64 * sizeof(float), stream);
        k_attn<<<dim3(64, (N + 255) / 256), 256, 0, stream>>>(buf_qkv, buf_acc, N);
        k_ln<<<(N + 3) / 4, 256, 0, stream>>>(buf_acc, buf_proj, l1g, l1b, buf_x, N);
        // ---- layer 2 ----
        k_gat_wh<<<(64 * N + 255) / 256, 256, 0, stream>>>(buf_x, g2W, buf_Wh, N, EMB);
        k_gat_s<<<(8 * N + 255) / 256, 256, 0, stream>>>(buf_Wh, g2a, buf_s1, buf_s2, N);
        k_gat_attn<<<N, 256, 0, stream>>>(adj, buf_s1, buf_s2, buf_Wh, buf_gat, N);
        k_proj<<<(64 * N + 255) / 256, 256, 0, stream>>>(buf_gat, p2W, buf_proj, N);
        k_qkv<<<(1536 * N + 255) / 256, 256, 0, stream>>>(buf_proj, s2W, s2b, buf_qkv, N);
        hipMemsetAsync(buf_acc, 0, (size_t)N * 64 * sizeof(float), stream);
        k_attn<<<dim3(64, (N + 255) / 256), 256, 0, stream>>>(buf_qkv, buf_acc, N);
        k_ln<<<(N + 3) / 4, 256, 0, stream>>>(buf_acc, buf_proj, l2g, l2b, xout, N);
    };

    run_branch(pfeat, padj, NPROT, 512, d_in + 5, buf_px);
    run_branch(dfeat, dadj, NDRUG, 256, d_in + 19, buf_dx);

    k_mlp<<<NPAIR, 128, 0, stream>>>(buf_px, buf_dx, pairs,
                                     fc1W, fc1b, fc2W, fc2b, fc3W, fc3b,
                                     (float*)d_out);
}